// Round 3
// baseline (207.950 us; speedup 1.0000x reference)
//
#include <hip/hip_runtime.h>
#include <hip/hip_bf16.h>

typedef __attribute__((ext_vector_type(8))) short short8;
typedef __attribute__((ext_vector_type(4))) float f32x4;

namespace {
constexpr int Nc  = 2048;   // N
constexpr int NXc = 4096;   // 2N
constexpr int Pc  = 64;
constexpr int Mc  = 4;
constexpr int Dc  = 256;
constexpr int BH  = 16;
constexpr float LOG2E = 1.4426950408889634f;
}

__device__ inline float fexp2(float x) {
#if __has_builtin(__builtin_amdgcn_exp2f)
  return __builtin_amdgcn_exp2f(x);
#else
  return exp2f(x);
#endif
}

__device__ inline unsigned int bfpack(float a, float b) {
  union { __hip_bfloat162 h; unsigned int u; } cv;
  cv.h = __float22bfloat162_rn(make_float2(a, b));
  return cv.u;
}

// Gather-only pre-pass: Wb[bh][m*256+d][64] = bf16( LOG2E * X[bh][SK[b,m,d]][:] )
// 8 threads per 64-elem row; 16384 rows total -> 512 blocks x 256.
__global__ __launch_bounds__(256) void prepass_kernel(
    const float* __restrict__ Q, const float* __restrict__ K,
    const int* __restrict__ SK, __hip_bfloat16* __restrict__ Wb)
{
  const int t  = blockIdx.x * 256 + threadIdx.x;
  const int q  = t & 7;
  const int r  = t >> 3;            // 0..16383
  const int bh = r >> 10;
  const int md = r & 1023;
  const int b  = bh >> 3;
  const int idx = SK[b * (Mc * Dc) + md];
  const float* src = (idx < Nc) ? (Q + ((size_t)bh * Nc + idx) * Pc)
                                : (K + ((size_t)bh * Nc + (idx - Nc)) * Pc);
  const f32x4* s4 = (const f32x4*)(src + q * 8);
  f32x4 f0 = s4[0], f1 = s4[1];
  uint4 u;
  u.x = bfpack(f0.x * LOG2E, f0.y * LOG2E);
  u.y = bfpack(f0.z * LOG2E, f0.w * LOG2E);
  u.z = bfpack(f1.x * LOG2E, f1.y * LOG2E);
  u.w = bfpack(f1.z * LOG2E, f1.w * LOG2E);
  *(uint4*)(Wb + (size_t)r * Pc + q * 8) = u;
}

// Main: block = 64 n-rows x 256 d, one bh. Wave wv owns 16 n-rows, all 256 d.
// MFMA: A = W rows (d), B = X rows (n)  =>  C: row=d (quad*4+reg), col=n (lane&15).
// Lane's 4 C-regs = 4 consecutive d -> f32x4 stores. W frags read straight from
// L2-resident Wb; X frags loaded fp32 once and converted in-register. 1 barrier.
__global__ __launch_bounds__(256, 3) void sketch_main(
    const float* __restrict__ Q, const float* __restrict__ K,
    const __hip_bfloat16* __restrict__ Wb,
    const float* __restrict__ SGN, float* __restrict__ OUT)
{
  __shared__ float Ss[Mc * Dc];   // 4 KB sign table

  const int t    = threadIdx.x;
  const int lane = t & 63;
  const int wv   = t >> 6;
  const int brow = lane & 15;
  const int q    = lane >> 4;
  const int bh   = blockIdx.y;
  const int n0   = blockIdx.x * 64;

  for (int i = t; i < Mc * Dc; i += 256) Ss[i] = SGN[i];

  // X B-fragment: lane holds X[n0+wv*16+brow][k = khalf*32 + q*8 + j]
  const int nrow = n0 + wv * 16 + brow;
  const float* xsrc = (n0 < Nc) ? (Q + ((size_t)bh * Nc + nrow) * Pc)
                                : (K + ((size_t)bh * Nc + (nrow - Nc)) * Pc);
  f32x4 x0 = *(const f32x4*)(xsrc + q * 8);
  f32x4 x1 = *(const f32x4*)(xsrc + q * 8 + 4);
  f32x4 x2 = *(const f32x4*)(xsrc + 32 + q * 8);
  f32x4 x3 = *(const f32x4*)(xsrc + 32 + q * 8 + 4);
  short8 bfr0, bfr1;
  {
    union { short8 s; uint4 u; } c0, c1;
    c0.u.x = bfpack(x0.x, x0.y); c0.u.y = bfpack(x0.z, x0.w);
    c0.u.z = bfpack(x1.x, x1.y); c0.u.w = bfpack(x1.z, x1.w);
    c1.u.x = bfpack(x2.x, x2.y); c1.u.y = bfpack(x2.z, x2.w);
    c1.u.z = bfpack(x3.x, x3.y); c1.u.w = bfpack(x3.z, x3.w);
    bfr0 = c0.s; bfr1 = c1.s;
  }

  __syncthreads();  // Ss ready

  const __hip_bfloat16* wb = Wb + (size_t)bh * (Mc * Dc) * Pc;

  f32x4 AS[16];
  #pragma unroll
  for (int dt = 0; dt < 16; ++dt) AS[dt] = (f32x4){0.f, 0.f, 0.f, 0.f};

  for (int m = 0; m < Mc; ++m) {
    const __hip_bfloat16* wm = wb + (size_t)m * Dc * Pc;
    #pragma unroll 4
    for (int dt = 0; dt < 16; ++dt) {
      // A-frag: lane holds W[dt*16+brow][k = khalf*32 + q*8 + j]
      const __hip_bfloat16* wrow = wm + (size_t)(dt * 16 + brow) * Pc + q * 8;
      short8 a0 = *(const short8*)wrow;
      short8 a1 = *(const short8*)(wrow + 32);
      f32x4 c = {0.f, 0.f, 0.f, 0.f};
      c = __builtin_amdgcn_mfma_f32_16x16x32_bf16(a0, bfr0, c, 0, 0, 0);
      c = __builtin_amdgcn_mfma_f32_16x16x32_bf16(a1, bfr1, c, 0, 0, 0);
      const f32x4 sg = *(const f32x4*)&Ss[m * Dc + dt * 16 + q * 4];
      AS[dt].x = fmaf(sg.x, fexp2(c.x), AS[dt].x);
      AS[dt].y = fmaf(sg.y, fexp2(c.y), AS[dt].y);
      AS[dt].z = fmaf(sg.z, fexp2(c.z), AS[dt].z);
      AS[dt].w = fmaf(sg.w, fexp2(c.w), AS[dt].w);
    }
  }

  // Store: row n = nrow, d = dt*16 + q*4 + {0..3}; per instr: 16 rows x 64 B.
  float* orow = OUT + ((size_t)bh * NXc + nrow) * Dc + q * 4;
  #pragma unroll
  for (int dt = 0; dt < 16; ++dt)
    __builtin_nontemporal_store(AS[dt], (f32x4*)(orow + dt * 16));
}

extern "C" void kernel_launch(void* const* d_in, const int* in_sizes, int n_in,
                              void* d_out, int out_size, void* d_ws, size_t ws_size,
                              hipStream_t stream) {
  (void)in_sizes; (void)n_in; (void)out_size; (void)ws_size;
  const float* Q   = (const float*)d_in[0];
  const float* K   = (const float*)d_in[1];
  const int*   SK  = (const int*)d_in[2];
  const float* SGN = (const float*)d_in[3];
  float* OUT = (float*)d_out;

  __hip_bfloat16* Wb = (__hip_bfloat16*)d_ws;  // 2 MiB

  prepass_kernel<<<dim3(512), dim3(256), 0, stream>>>(Q, K, SK, Wb);
  sketch_main<<<dim3(NXc / 64, BH), dim3(256), 0, stream>>>(Q, K, Wb, SGN, OUT);
}

// Round 4
// 205.154 us; speedup vs baseline: 1.0136x; 1.0136x over previous
//
#include <hip/hip_runtime.h>
#include <hip/hip_bf16.h>

typedef __attribute__((ext_vector_type(8))) short short8;
typedef __attribute__((ext_vector_type(4))) float f32x4;

namespace {
constexpr int Nc  = 2048;   // N
constexpr int NXc = 4096;   // 2N
constexpr int Pc  = 64;
constexpr int Mc  = 4;
constexpr int Dc  = 256;
constexpr int BH  = 16;
constexpr float LOG2E = 1.4426950408889634f;
}

__device__ inline float fexp2(float x) {
#if __has_builtin(__builtin_amdgcn_exp2f)
  return __builtin_amdgcn_exp2f(x);
#else
  return exp2f(x);
#endif
}

__device__ inline unsigned int bfpack(float a, float b) {
  union { __hip_bfloat162 h; unsigned int u; } cv;
  cv.h = __float22bfloat162_rn(make_float2(a, b));
  return cv.u;
}

// Gather-only pre-pass: Wb[bh][m*256+d][64] = bf16( LOG2E * X[bh][SK[b,m,d]][:] )
// 8 threads per row; per wave-instr the stores cover 8 full 128 B rows (no
// partial-line writes).
__global__ __launch_bounds__(256) void prepass_kernel(
    const float* __restrict__ Q, const float* __restrict__ K,
    const int* __restrict__ SK, __hip_bfloat16* __restrict__ Wb)
{
  const int t  = blockIdx.x * 256 + threadIdx.x;
  const int q  = t & 7;
  const int r  = t >> 3;            // 0..16383
  const int bh = r >> 10;
  const int md = r & 1023;
  const int b  = bh >> 3;
  const int idx = SK[b * (Mc * Dc) + md];
  const float* src = (idx < Nc) ? (Q + ((size_t)bh * Nc + idx) * Pc)
                                : (K + ((size_t)bh * Nc + (idx - Nc)) * Pc);
  const f32x4* s4 = (const f32x4*)(src + q * 8);
  f32x4 f0 = s4[0], f1 = s4[1];
  uint4 u;
  u.x = bfpack(f0.x * LOG2E, f0.y * LOG2E);
  u.y = bfpack(f0.z * LOG2E, f0.w * LOG2E);
  u.z = bfpack(f1.x * LOG2E, f1.y * LOG2E);
  u.w = bfpack(f1.z * LOG2E, f1.w * LOG2E);
  *(uint4*)(Wb + (size_t)r * Pc + q * 8) = u;
}

// Main: block = 64 n-rows x 256 d, one bh. Wave wv owns 16 n-rows, all 256 d.
// MFMA: A = W rows (d), B = X rows (n) => C: row=d (quad*4+reg), col=n (lane&15).
// Epilogue: per-wave XOR-swizzled LDS transpose so every global store instr
// writes two full 512 B row-halves (only complete 128 B lines -> no RMW).
__global__ __launch_bounds__(256, 4) void sketch_main(
    const float* __restrict__ Q, const float* __restrict__ K,
    const __hip_bfloat16* __restrict__ Wb,
    const float* __restrict__ SGN, float* __restrict__ OUT)
{
  __shared__ float Ts[4][16][128];  // 32 KB: per-wave transpose buffer (half-tile)
  __shared__ float Ss[Mc * Dc];     //  4 KB sign table

  const int t    = threadIdx.x;
  const int lane = t & 63;
  const int wv   = t >> 6;
  const int brow = lane & 15;
  const int q    = lane >> 4;
  const int bh   = blockIdx.y;
  const int n0   = blockIdx.x * 64;

  for (int i = t; i < Mc * Dc; i += 256) Ss[i] = SGN[i];

  // X B-fragment: lane holds X[n0+wv*16+brow][k = khalf*32 + q*8 + j]
  const int nrow = n0 + wv * 16 + brow;
  const float* xsrc = (n0 < Nc) ? (Q + ((size_t)bh * Nc + nrow) * Pc)
                                : (K + ((size_t)bh * Nc + (nrow - Nc)) * Pc);
  f32x4 x0 = *(const f32x4*)(xsrc + q * 8);
  f32x4 x1 = *(const f32x4*)(xsrc + q * 8 + 4);
  f32x4 x2 = *(const f32x4*)(xsrc + 32 + q * 8);
  f32x4 x3 = *(const f32x4*)(xsrc + 32 + q * 8 + 4);
  short8 bfr0, bfr1;
  {
    union { short8 s; uint4 u; } c0, c1;
    c0.u.x = bfpack(x0.x, x0.y); c0.u.y = bfpack(x0.z, x0.w);
    c0.u.z = bfpack(x1.x, x1.y); c0.u.w = bfpack(x1.z, x1.w);
    c1.u.x = bfpack(x2.x, x2.y); c1.u.y = bfpack(x2.z, x2.w);
    c1.u.z = bfpack(x3.x, x3.y); c1.u.w = bfpack(x3.z, x3.w);
    bfr0 = c0.s; bfr1 = c1.s;
  }

  __syncthreads();  // Ss ready

  const __hip_bfloat16* wb = Wb + (size_t)bh * (Mc * Dc) * Pc;

  f32x4 AS[16];
  #pragma unroll
  for (int dt = 0; dt < 16; ++dt) AS[dt] = (f32x4){0.f, 0.f, 0.f, 0.f};

  for (int m = 0; m < Mc; ++m) {
    const __hip_bfloat16* wm = wb + (size_t)m * Dc * Pc;
    #pragma unroll 4
    for (int dt = 0; dt < 16; ++dt) {
      // A-frag: lane holds W[dt*16+brow][k = khalf*32 + q*8 + j]
      const __hip_bfloat16* wrow = wm + (size_t)(dt * 16 + brow) * Pc + q * 8;
      short8 a0 = *(const short8*)wrow;
      short8 a1 = *(const short8*)(wrow + 32);
      f32x4 c = {0.f, 0.f, 0.f, 0.f};
      c = __builtin_amdgcn_mfma_f32_16x16x32_bf16(a0, bfr0, c, 0, 0, 0);
      c = __builtin_amdgcn_mfma_f32_16x16x32_bf16(a1, bfr1, c, 0, 0, 0);
      const f32x4 sg = *(const f32x4*)&Ss[m * Dc + dt * 16 + q * 4];
      AS[dt].x = fmaf(sg.x, fexp2(c.x), AS[dt].x);
      AS[dt].y = fmaf(sg.y, fexp2(c.y), AS[dt].y);
      AS[dt].z = fmaf(sg.z, fexp2(c.z), AS[dt].z);
      AS[dt].w = fmaf(sg.w, fexp2(c.w), AS[dt].w);
    }
  }

  // Epilogue: two halves (d in [h*128, h*128+128)). Write swizzled, barrier,
  // read row-major, store full 512 B row-halves.
  float* orow_base = OUT + ((size_t)bh * NXc + n0 + wv * 16) * Dc;
  #pragma unroll
  for (int h = 0; h < 2; ++h) {
    #pragma unroll
    for (int j = 0; j < 8; ++j) {
      const int c = (j * 16 + q * 4) ^ ((brow & 7) * 4);
      *(f32x4*)&Ts[wv][brow][c] = AS[h * 8 + j];
    }
    __syncthreads();
    #pragma unroll
    for (int i = 0; i < 8; ++i) {
      const int r  = i * 2 + (lane >> 5);
      const int c2 = ((lane & 31) * 4) ^ ((r & 7) * 4);
      f32x4 v = *(const f32x4*)&Ts[wv][r][c2];
      float* dst = orow_base + (size_t)r * Dc + h * 128 + (lane & 31) * 4;
      __builtin_nontemporal_store(v, (f32x4*)dst);
    }
    __syncthreads();
  }
}

extern "C" void kernel_launch(void* const* d_in, const int* in_sizes, int n_in,
                              void* d_out, int out_size, void* d_ws, size_t ws_size,
                              hipStream_t stream) {
  (void)in_sizes; (void)n_in; (void)out_size; (void)ws_size;
  const float* Q   = (const float*)d_in[0];
  const float* K   = (const float*)d_in[1];
  const int*   SK  = (const int*)d_in[2];
  const float* SGN = (const float*)d_in[3];
  float* OUT = (float*)d_out;

  __hip_bfloat16* Wb = (__hip_bfloat16*)d_ws;  // 2 MiB

  prepass_kernel<<<dim3(512), dim3(256), 0, stream>>>(Q, K, SK, Wb);
  sketch_main<<<dim3(NXc / 64, BH), dim3(256), 0, stream>>>(Q, K, Wb, SGN, OUT);
}

// Round 5
// 102.197 us; speedup vs baseline: 2.0348x; 2.0074x over previous
//
#include <hip/hip_runtime.h>
#include <hip/hip_bf16.h>

typedef __attribute__((ext_vector_type(8))) short short8;
typedef __attribute__((ext_vector_type(4))) float f32x4;

namespace {
constexpr int Nc  = 2048;   // N
constexpr int NXc = 4096;   // 2N
constexpr int Pc  = 64;
constexpr int Mc  = 4;
constexpr int Dc  = 256;
constexpr int BH  = 16;
constexpr int LDW = 72;     // padded LDS row stride (bf16)
constexpr float LOG2E = 1.4426950408889634f;
}

__device__ inline float fexp2(float x) {
#if __has_builtin(__builtin_amdgcn_exp2f)
  return __builtin_amdgcn_exp2f(x);
#else
  return exp2f(x);
#endif
}

__device__ inline unsigned int bfpack(float a, float b) {
  union { __hip_bfloat162 h; unsigned int u; } cv;
  cv.h = __float22bfloat162_rn(make_float2(a, b));
  return cv.u;
}

// Gather-only pre-pass: Wb[bh][m*256+d][64] = bf16( LOG2E * X[bh][SK[b,m,d]][:] )
__global__ __launch_bounds__(256) void prepass_kernel(
    const float* __restrict__ Q, const float* __restrict__ K,
    const int* __restrict__ SK, __hip_bfloat16* __restrict__ Wb)
{
  const int t  = blockIdx.x * 256 + threadIdx.x;
  const int q  = t & 7;
  const int r  = t >> 3;            // 0..16383
  const int bh = r >> 10;
  const int md = r & 1023;
  const int b  = bh >> 3;
  const int idx = SK[b * (Mc * Dc) + md];
  const float* src = (idx < Nc) ? (Q + ((size_t)bh * Nc + idx) * Pc)
                                : (K + ((size_t)bh * Nc + (idx - Nc)) * Pc);
  const f32x4* s4 = (const f32x4*)(src + q * 8);
  f32x4 f0 = s4[0], f1 = s4[1];
  uint4 u;
  u.x = bfpack(f0.x * LOG2E, f0.y * LOG2E);
  u.y = bfpack(f0.z * LOG2E, f0.w * LOG2E);
  u.z = bfpack(f1.x * LOG2E, f1.y * LOG2E);
  u.w = bfpack(f1.z * LOG2E, f1.w * LOG2E);
  *(uint4*)(Wb + (size_t)r * Pc + q * 8) = u;
}

// Main: block = 64 n-rows, one bh. W streamed through double-buffered LDS
// (shared by all 4 waves), X B-frags converted fp32->bf16 in-register once.
// MFMA: A = W rows (d), B = X rows (n) => C: row=d (quad*4+reg), col=n.
// Lane's 4 C-regs = 4 consecutive d -> one cached f32x4 store per tile.
__global__ __launch_bounds__(256, 4) void sketch_main(
    const float* __restrict__ Q, const float* __restrict__ K,
    const __hip_bfloat16* __restrict__ Wb,
    const float* __restrict__ SGN, float* __restrict__ OUT)
{
  __shared__ __hip_bfloat16 Ws[2][64][LDW];  // 18432 B
  __shared__ float Ss[Mc * Dc];              //  4096 B

  const int t    = threadIdx.x;
  const int lane = t & 63;
  const int wv   = t >> 6;
  const int brow = lane & 15;
  const int q    = lane >> 4;
  const int bh   = blockIdx.y;
  const int n0   = blockIdx.x * 64;

  for (int i = t; i < Mc * Dc; i += 256) Ss[i] = SGN[i];

  // X B-fragment: lane holds X[n0+wv*16+brow][k = khalf*32 + q*8 + j]
  const int nrow = n0 + wv * 16 + brow;
  const float* xsrc = (n0 < Nc) ? (Q + ((size_t)bh * Nc + nrow) * Pc)
                                : (K + ((size_t)bh * Nc + (nrow - Nc)) * Pc);
  f32x4 x0 = *(const f32x4*)(xsrc + q * 8);
  f32x4 x1 = *(const f32x4*)(xsrc + q * 8 + 4);
  f32x4 x2 = *(const f32x4*)(xsrc + 32 + q * 8);
  f32x4 x3 = *(const f32x4*)(xsrc + 32 + q * 8 + 4);
  short8 bfr0, bfr1;
  {
    union { short8 s; uint4 u; } c0, c1;
    c0.u.x = bfpack(x0.x, x0.y); c0.u.y = bfpack(x0.z, x0.w);
    c0.u.z = bfpack(x1.x, x1.y); c0.u.w = bfpack(x1.z, x1.w);
    c1.u.x = bfpack(x2.x, x2.y); c1.u.y = bfpack(x2.z, x2.w);
    c1.u.z = bfpack(x3.x, x3.y); c1.u.w = bfpack(x3.z, x3.w);
    bfr0 = c0.s; bfr1 = c1.s;
  }

  const __hip_bfloat16* wbase = Wb + (size_t)bh * (Mc * Dc) * Pc;
  const int tr = t >> 2;        // staging row 0..63
  const int tq = t & 3;         // 16-elem quarter

  // phase p = dc*4 + m; W chunk rows [crow(p), crow(p)+64) of the 1024
  auto crow = [](int p) { return (p & 3) * Dc + (p >> 2) * 64; };

  // preload chunk 0 into buf 0
  {
    const __hip_bfloat16* wp = wbase + (size_t)(crow(0) + tr) * Pc + tq * 16;
    uint4 wa = *(const uint4*)wp;
    uint4 wb = *(const uint4*)(wp + 8);
    *(uint4*)&Ws[0][tr][tq * 16]     = wa;
    *(uint4*)&Ws[0][tr][tq * 16 + 8] = wb;
  }
  __syncthreads();

  f32x4 AS[4];
  #pragma unroll
  for (int dt = 0; dt < 4; ++dt) AS[dt] = (f32x4){0.f, 0.f, 0.f, 0.f};

  for (int p = 0; p < 16; ++p) {
    // issue next chunk's global loads early (overlap with compute)
    const int pn = (p < 15) ? p + 1 : 15;
    const __hip_bfloat16* wp = wbase + (size_t)(crow(pn) + tr) * Pc + tq * 16;
    uint4 wa = *(const uint4*)wp;
    uint4 wb = *(const uint4*)(wp + 8);

    const int buf = p & 1;
    const int m   = p & 3;
    const int dc  = p >> 2;

    #pragma unroll
    for (int dt = 0; dt < 4; ++dt) {
      // A-frag: lane holds W[dt*16+brow][k = khalf*32 + q*8 + j]
      short8 a0 = *(const short8*)&Ws[buf][dt * 16 + brow][q * 8];
      short8 a1 = *(const short8*)&Ws[buf][dt * 16 + brow][32 + q * 8];
      f32x4 c = {0.f, 0.f, 0.f, 0.f};
      c = __builtin_amdgcn_mfma_f32_16x16x32_bf16(a0, bfr0, c, 0, 0, 0);
      c = __builtin_amdgcn_mfma_f32_16x16x32_bf16(a1, bfr1, c, 0, 0, 0);
      const f32x4 sg = *(const f32x4*)&Ss[m * Dc + dc * 64 + dt * 16 + q * 4];
      AS[dt].x = fmaf(sg.x, fexp2(c.x), AS[dt].x);
      AS[dt].y = fmaf(sg.y, fexp2(c.y), AS[dt].y);
      AS[dt].z = fmaf(sg.z, fexp2(c.z), AS[dt].z);
      AS[dt].w = fmaf(sg.w, fexp2(c.w), AS[dt].w);
    }

    if (m == 3) {
      // store: n = nrow (col), d = dc*64 + dt*16 + q*4 + reg -> f32x4, cached
      float* orow = OUT + ((size_t)bh * NXc + nrow) * Dc + dc * 64 + q * 4;
      #pragma unroll
      for (int dt = 0; dt < 4; ++dt) {
        *(f32x4*)(orow + dt * 16) = AS[dt];
        AS[dt] = (f32x4){0.f, 0.f, 0.f, 0.f};
      }
    }

    // stage next chunk into the other buffer
    *(uint4*)&Ws[buf ^ 1][tr][tq * 16]     = wa;
    *(uint4*)&Ws[buf ^ 1][tr][tq * 16 + 8] = wb;
    __syncthreads();
  }
}

extern "C" void kernel_launch(void* const* d_in, const int* in_sizes, int n_in,
                              void* d_out, int out_size, void* d_ws, size_t ws_size,
                              hipStream_t stream) {
  (void)in_sizes; (void)n_in; (void)out_size; (void)ws_size;
  const float* Q   = (const float*)d_in[0];
  const float* K   = (const float*)d_in[1];
  const int*   SK  = (const int*)d_in[2];
  const float* SGN = (const float*)d_in[3];
  float* OUT = (float*)d_out;

  __hip_bfloat16* Wb = (__hip_bfloat16*)d_ws;  // 2 MiB

  prepass_kernel<<<dim3(512), dim3(256), 0, stream>>>(Q, K, SK, Wb);
  sketch_main<<<dim3(NXc / 64, BH), dim3(256), 0, stream>>>(Q, K, Wb, SGN, OUT);
}